// Round 7
// baseline (41.878 us; speedup 1.0000x reference)
//
#include <hip/hip_runtime.h>
#include <hip/hip_bf16.h>
#include <math.h>

#define BB 64
#define LL 512
#define HH 768
#define SS 32
#define MM 2048
#define EPS_LN 1e-12f
#define EPS_COS 1e-8f

#define NKS 24                  // k-steps of 32
#define NGB 384                 // gemm blocks (64m x 64n tiles: 32 x 12)
#define CH_PER_G (NKS * 2 * 64) // short8 chunks per row-group
#define A_RG (MM / 16)          // 128
#define B_RG (HH / 16)          // 48
#define LDST 772                // LDS row stride (floats)

typedef __attribute__((ext_vector_type(8))) short short8;
typedef __attribute__((ext_vector_type(4))) float f32x4;

static __device__ inline unsigned short f2bf(float x) {
    __hip_bfloat16 h = __float2bfloat16(x);
    unsigned short b; __builtin_memcpy(&b, &h, 2); return b;
}
static __device__ inline float bf2f(unsigned short b) {
    __hip_bfloat16 h; __builtin_memcpy(&h, &b, 2); return __bfloat162float(h);
}

// K1: bid [0,64): segmean + LN(g2,b2) -> sel, sgs, sbs, selnorm (+consts for b==0)
//     bid [64,192): split gp row-group; [192,240): split W row-group.
// Fragment-linear chunk: dst[((rg*NKS+ks)*2+plane)*64 + lane]; lane l holds
// row rg*16+(l&15), k = ks*32+(l>>4)*8 .. +8.
__global__ __launch_bounds__(256) void k_prep(
    const float* __restrict__ gp, const float* __restrict__ Wm,
    const float* __restrict__ hs,
    const float* __restrict__ g1, const float* __restrict__ b1,
    const float* __restrict__ g2, const float* __restrict__ b2,
    const int* __restrict__ gstart, const int* __restrict__ gend,
    short8* __restrict__ a_ws, short8* __restrict__ b_ws,
    float* __restrict__ sel,        // [BB][HH]
    float* __restrict__ sgs, float* __restrict__ sbs,
    float* __restrict__ selnorm, float* __restrict__ consts)  // consts[3]
{
    __shared__ __align__(16) float xs[16][LDST];   // 49.4 KB
    __shared__ float red[6][4];
    __shared__ float sh2[2];
    const int bid = blockIdx.x;
    const int t = threadIdx.x;

    if (bid < BB) {
        const int b = bid;
        const int s0 = gstart[b], e0 = gend[b];
        const float inv = 1.0f / fmaxf((float)(e0 - s0), 1.0f);
        const float* base = hs + (size_t)b * LL * HH;
        const int c0 = t, c1 = t + 256, c2 = t + 512;
        float a[3][4];
#pragma unroll
        for (int j = 0; j < 3; ++j)
#pragma unroll
            for (int u = 0; u < 4; ++u) a[j][u] = 0.f;
        int l = s0;
        for (; l + 4 <= e0; l += 4) {
#pragma unroll
            for (int u = 0; u < 4; ++u) {
                const float* row = base + (size_t)(l + u) * HH;
                a[0][u] += row[c0]; a[1][u] += row[c1]; a[2][u] += row[c2];
            }
        }
        for (; l < e0; ++l) {
            const float* row = base + (size_t)l * HH;
            a[0][0] += row[c0]; a[1][0] += row[c1]; a[2][0] += row[c2];
        }
        const float v0 = ((a[0][0] + a[0][1]) + (a[0][2] + a[0][3])) * inv;
        const float v1 = ((a[1][0] + a[1][1]) + (a[1][2] + a[1][3])) * inv;
        const float v2 = ((a[2][0] + a[2][1]) + (a[2][2] + a[2][3])) * inv;

        float s = v0 + v1 + v2;
        float q = v0 * v0 + v1 * v1 + v2 * v2;
        for (int o = 32; o > 0; o >>= 1) {
            s += __shfl_down(s, o, 64);
            q += __shfl_down(q, o, 64);
        }
        const int lane = t & 63, wid = t >> 6;
        if (lane == 0) { red[0][wid] = s; red[1][wid] = q; }
        __syncthreads();
        if (t == 0) {
            const float ts = red[0][0] + red[0][1] + red[0][2] + red[0][3];
            const float tq = red[1][0] + red[1][1] + red[1][2] + red[1][3];
            const float mu = ts / (float)HH;
            const float var = tq / (float)HH - mu * mu;
            sh2[0] = mu; sh2[1] = rsqrtf(var + EPS_LN);
        }
        __syncthreads();
        const float mu = sh2[0], rinv = sh2[1];
        const float g1c0 = g1[c0], g1c1 = g1[c1], g1c2 = g1[c2];
        const float b1c0 = b1[c0], b1c1 = b1[c1], b1c2 = b1[c2];
        const float y0 = (v0 - mu) * rinv * g2[c0] + b2[c0];
        const float y1 = (v1 - mu) * rinv * g2[c1] + b2[c1];
        const float y2 = (v2 - mu) * rinv * g2[c2] + b2[c2];
        sel[(size_t)b * HH + c0] = y0;
        sel[(size_t)b * HH + c1] = y1;
        sel[(size_t)b * HH + c2] = y2;
        float gs = g1c0 * y0 + g1c1 * y1 + g1c2 * y2;
        float bs = b1c0 * y0 + b1c1 * y1 + b1c2 * y2;
        float n  = y0 * y0 + y1 * y1 + y2 * y2;
        float cg2 = g1c0 * g1c0 + g1c1 * g1c1 + g1c2 * g1c2;
        float cgb = g1c0 * b1c0 + g1c1 * b1c1 + g1c2 * b1c2;
        float cb2 = b1c0 * b1c0 + b1c1 * b1c1 + b1c2 * b1c2;
        for (int o = 32; o > 0; o >>= 1) {
            gs += __shfl_down(gs, o, 64);
            bs += __shfl_down(bs, o, 64);
            n  += __shfl_down(n, o, 64);
            cg2 += __shfl_down(cg2, o, 64);
            cgb += __shfl_down(cgb, o, 64);
            cb2 += __shfl_down(cb2, o, 64);
        }
        if (lane == 0) {
            red[0][wid] = gs; red[1][wid] = bs; red[2][wid] = n;
            red[3][wid] = cg2; red[4][wid] = cgb; red[5][wid] = cb2;
        }
        __syncthreads();
        if (t == 0) {
            sgs[b] = red[0][0] + red[0][1] + red[0][2] + red[0][3];
            sbs[b] = red[1][0] + red[1][1] + red[1][2] + red[1][3];
            selnorm[b] = sqrtf(red[2][0] + red[2][1] + red[2][2] + red[2][3]);
            if (b == 0) {
                consts[0] = red[3][0] + red[3][1] + red[3][2] + red[3][3];
                consts[1] = red[4][0] + red[4][1] + red[4][2] + red[4][3];
                consts[2] = red[5][0] + red[5][1] + red[5][2] + red[5][3];
            }
        }
    } else {
        const bool isA = bid < BB + A_RG;
        const int rg = isA ? (bid - BB) : (bid - BB - A_RG);
        const float* src = (isA ? gp : Wm) + (size_t)rg * 16 * HH;
        short8* dst = isA ? a_ws : b_ws;

        // coalesced stage: 16 rows x 768 floats, contiguous in global
#pragma unroll
        for (int j = 0; j < 12; ++j) {
            const int idx = t + j * 256;        // 0..3071 float4s
            const int row = idx / 192;
            const int col = (idx - row * 192) * 4;
            *(float4*)&xs[row][col] = *(const float4*)(src + (size_t)idx * 4);
        }
        __syncthreads();

        const int l = t & 63;
        const int cslot = t >> 6;               // 0..3
        const int row = l & 15;
        const int kq = (l >> 4) * 8;
#pragma unroll
        for (int i = 0; i < 6; ++i) {
            const int ks = i * 4 + cslot;
            float xv[8];
            *(float4*)&xv[0] = *(const float4*)&xs[row][ks * 32 + kq];
            *(float4*)&xv[4] = *(const float4*)&xs[row][ks * 32 + kq + 4];
            union { unsigned short u[8]; short8 v; } Hc, Lc;
#pragma unroll
            for (int j = 0; j < 8; ++j) {
                const unsigned short hb = f2bf(xv[j]);
                Hc.u[j] = hb;
                Lc.u[j] = f2bf(xv[j] - bf2f(hb));
            }
            dst[((size_t)(rg * NKS + ks) * 2) * 64 + l]     = Hc.v;
            dst[((size_t)(rg * NKS + ks) * 2 + 1) * 64 + l] = Lc.v;
        }
    }
}

// K2: t = gp @ W^T via 3-term bf16-split MFMA (no LDS, no barriers), then the
// LN+cosine epilogue reduced ALGEBRAICALLY to 6 linear partials per row over
// this block's 64 cols, written to pp2[row][nb][6].
#define TRI(ACC, AH_, AL_, BH_, BL_) \
    ACC = __builtin_amdgcn_mfma_f32_16x16x32_bf16(AH_, BH_, ACC, 0, 0, 0); \
    ACC = __builtin_amdgcn_mfma_f32_16x16x32_bf16(AH_, BL_, ACC, 0, 0, 0); \
    ACC = __builtin_amdgcn_mfma_f32_16x16x32_bf16(AL_, BH_, ACC, 0, 0, 0);

#define DECLSET(P) short8 P##a0h,P##a0l,P##a1h,P##a1l, \
    P##b0h,P##b0l,P##b1h,P##b1l,P##b2h,P##b2l,P##b3h,P##b3l;

#define LOADSET(P, KS) { const int o_ = (KS) * 128; \
    P##a0h = ba0[o_]; P##a0l = ba0[o_ + 64]; P##a1h = ba1[o_]; P##a1l = ba1[o_ + 64]; \
    P##b0h = bb0[o_]; P##b0l = bb0[o_ + 64]; P##b1h = bb1[o_]; P##b1l = bb1[o_ + 64]; \
    P##b2h = bb2[o_]; P##b2l = bb2[o_ + 64]; P##b3h = bb3[o_]; P##b3l = bb3[o_ + 64]; }

#define MFMASET(P) \
    TRI(acc[0][0], P##a0h, P##a0l, P##b0h, P##b0l) \
    TRI(acc[0][1], P##a0h, P##a0l, P##b1h, P##b1l) \
    TRI(acc[0][2], P##a0h, P##a0l, P##b2h, P##b2l) \
    TRI(acc[0][3], P##a0h, P##a0l, P##b3h, P##b3l) \
    TRI(acc[1][0], P##a1h, P##a1l, P##b0h, P##b0l) \
    TRI(acc[1][1], P##a1h, P##a1l, P##b1h, P##b1l) \
    TRI(acc[1][2], P##a1h, P##a1l, P##b2h, P##b2l) \
    TRI(acc[1][3], P##a1h, P##a1l, P##b3h, P##b3l)

__global__ __launch_bounds__(128) void k_gemm(
    const short8* __restrict__ aw, const short8* __restrict__ bw,
    const float* __restrict__ bias,
    const float* __restrict__ g1, const float* __restrict__ b1,
    const float* __restrict__ sel,
    float* __restrict__ pp2)        // [MM][12][6]
{
    const int orig = blockIdx.x;
    const int bid = (orig & 7) * 48 + (orig >> 3);   // XCD swizzle (384 % 8 == 0)
    const int mb = bid / 12;
    const int nb = bid - mb * 12;
    const int wave = threadIdx.x >> 6;
    const int lane = threadIdx.x & 63;

    const int mg0 = mb * 4 + wave * 2;
    const short8* ba0 = aw + (size_t)mg0 * CH_PER_G + lane;
    const short8* ba1 = ba0 + CH_PER_G;
    const short8* bb0 = bw + (size_t)(nb * 4) * CH_PER_G + lane;
    const short8* bb1 = bb0 + CH_PER_G;
    const short8* bb2 = bb1 + CH_PER_G;
    const short8* bb3 = bb2 + CH_PER_G;

    f32x4 acc[2][4] = {};
    DECLSET(A) DECLSET(C)

    LOADSET(A, 0)
    for (int ks = 0; ks < NKS - 2; ks += 2) {
        LOADSET(C, ks + 1)
        MFMASET(A)
        LOADSET(A, ks + 2)
        MFMASET(C)
    }
    LOADSET(C, NKS - 1)
    MFMASET(A)
    MFMASET(C)

    // ---- fused epilogue: 6 linear partials per row over this block's cols ----
    const int cc = lane & 15;
    const int g = lane >> 4;
    const int wn = nb * 64;
    const int bw_ = mb * 2 + wave;          // batch of this wave's 32 rows
    float bias_c[4], gg2[4], ggb[4], ggs[4];
#pragma unroll
    for (int ni = 0; ni < 4; ++ni) {
        const int c = wn + ni * 16 + cc;
        const float g1c = g1[c], b1c = b1[c];
        bias_c[ni] = bias[c];
        gg2[ni] = g1c * g1c;
        ggb[ni] = g1c * b1c;
        ggs[ni] = g1c * sel[(size_t)bw_ * HH + c];
    }
    float P[2][4][6];
#pragma unroll
    for (int mi = 0; mi < 2; ++mi)
#pragma unroll
        for (int j = 0; j < 4; ++j)
#pragma unroll
            for (int q = 0; q < 6; ++q) P[mi][j][q] = 0.f;
#pragma unroll
    for (int mi = 0; mi < 2; ++mi)
#pragma unroll
        for (int ni = 0; ni < 4; ++ni)
#pragma unroll
            for (int j = 0; j < 4; ++j) {
                const float tv = acc[mi][ni][j] + bias_c[ni];
                const float tg = tv * gg2[ni];
                P[mi][j][0] += tv;
                P[mi][j][1] = fmaf(tv, tv, P[mi][j][1]);
                P[mi][j][2] += tg;
                P[mi][j][3] = fmaf(tg, tv, P[mi][j][3]);
                P[mi][j][4] = fmaf(tv, ggb[ni], P[mi][j][4]);
                P[mi][j][5] = fmaf(tv, ggs[ni], P[mi][j][5]);
            }
    // reduce across the 16 lanes holding this row's cols
#pragma unroll
    for (int mi = 0; mi < 2; ++mi)
#pragma unroll
        for (int j = 0; j < 4; ++j)
#pragma unroll
            for (int q = 0; q < 6; ++q) {
                float v = P[mi][j][q];
                v += __shfl_xor(v, 1, 64);
                v += __shfl_xor(v, 2, 64);
                v += __shfl_xor(v, 4, 64);
                v += __shfl_xor(v, 8, 64);
                P[mi][j][q] = v;
            }
    if (cc == 0) {
#pragma unroll
        for (int mi = 0; mi < 2; ++mi)
#pragma unroll
            for (int j = 0; j < 4; ++j) {
                const int row = mg0 * 16 + mi * 16 + g * 4 + j;
                float* dst = pp2 + ((size_t)row * 12 + nb) * 6;
#pragma unroll
                for (int q = 0; q < 6; ++q) dst[q] = P[mi][j][q];
            }
    }
}

// K3: final per-row scalar math from the 12 partial sets. 8 blocks x 256.
__global__ __launch_bounds__(256) void k_comb(
    const float* __restrict__ pp2,
    const float* __restrict__ sgs, const float* __restrict__ sbs,
    const float* __restrict__ selnorm, const float* __restrict__ consts,
    float* __restrict__ out)
{
    const int m = blockIdx.x * 256 + threadIdx.x;
    const float* p = pp2 + (size_t)m * 72;
    float S0 = 0.f, S1 = 0.f, S2 = 0.f, S3 = 0.f, S4 = 0.f, S5 = 0.f;
#pragma unroll
    for (int nb = 0; nb < 12; ++nb) {
        S0 += p[nb * 6 + 0]; S1 += p[nb * 6 + 1]; S2 += p[nb * 6 + 2];
        S3 += p[nb * 6 + 3]; S4 += p[nb * 6 + 4]; S5 += p[nb * 6 + 5];
    }
    const int b = m >> 5;
    const float mu = S0 * (1.0f / (float)HH);
    const float var = S1 * (1.0f / (float)HH) - mu * mu;
    const float rinv = rsqrtf(var + EPS_LN);
    const float num = rinv * (S5 - mu * sgs[b]) + sbs[b];
    const float ny2 = rinv * rinv * (S3 - 2.f * mu * S2 + mu * mu * consts[0])
                    + 2.f * rinv * (S4 - mu * consts[1]) + consts[2];
    const float ny = sqrtf(fmaxf(ny2, 0.f));
    out[m] = num / fmaxf(selnorm[b] * ny, EPS_COS);
}

extern "C" void kernel_launch(void* const* d_in, const int* in_sizes, int n_in,
                              void* d_out, int out_size, void* d_ws, size_t ws_size,
                              hipStream_t stream) {
    const float* hs  = (const float*)d_in[0];
    const float* gp  = (const float*)d_in[1];
    const float* W   = (const float*)d_in[2];
    const float* bia = (const float*)d_in[3];
    const float* g1  = (const float*)d_in[4];
    const float* b1  = (const float*)d_in[5];
    const float* g2  = (const float*)d_in[6];
    const float* b2  = (const float*)d_in[7];
    const int* gs    = (const int*)d_in[8];
    const int* ge    = (const int*)d_in[9];
    float* out = (float*)d_out;

    char* ws = (char*)d_ws;
    short8* a_ws  = (short8*)ws;                                        // 6.29 MB
    short8* b_ws  = (short8*)(ws + (size_t)A_RG * CH_PER_G * 16);       // 2.36 MB
    float* sel     = (float*)(ws + (size_t)(A_RG + B_RG) * CH_PER_G * 16); // 196 KB
    float* pp2     = sel + (size_t)BB * HH;                             // 590 KB
    float* sgs     = pp2 + (size_t)MM * 12 * 6;
    float* sbs     = sgs + BB;
    float* selnorm = sbs + BB;
    float* consts  = selnorm + BB;

    k_prep<<<BB + A_RG + B_RG, 256, 0, stream>>>(gp, W, hs, g1, b1, g2, b2,
                                                 gs, ge, a_ws, b_ws,
                                                 sel, sgs, sbs, selnorm, consts);
    k_gemm<<<NGB, 128, 0, stream>>>(a_ws, b_ws, bia, g1, b1, sel, pp2);
    k_comb<<<MM / 256, 256, 0, stream>>>(pp2, sgs, sbs, selnorm, consts, out);
}

// Round 8
// 39.766 us; speedup vs baseline: 1.0531x; 1.0531x over previous
//
#include <hip/hip_runtime.h>
#include <hip/hip_bf16.h>
#include <math.h>

#define BB 64
#define LL 512
#define HH 768
#define SS 32
#define MM 2048
#define EPS_LN 1e-12f
#define EPS_COS 1e-8f

#define NKS 24                  // k-steps of 32
#define NGB 384                 // gemm blocks (64m x 64n tiles: 32 x 12)
#define CH_PER_G (NKS * 2 * 64) // short8 chunks per row-group
#define A_RG (MM / 16)          // 128
#define B_RG (HH / 16)          // 48
#define LDST 772                // LDS row stride (floats)
#define SEG_SLICES 8
#define SEG_BLK (BB * SEG_SLICES)   // 512
#define NT 24                   // n-tiles of 32 cols for partials

typedef __attribute__((ext_vector_type(8))) short short8;
typedef __attribute__((ext_vector_type(4))) float f32x4;

static __device__ inline unsigned short f2bf(float x) {
    __hip_bfloat16 h = __float2bfloat16(x);
    unsigned short b; __builtin_memcpy(&b, &h, 2); return b;
}
static __device__ inline float bf2f(unsigned short b) {
    __hip_bfloat16 h; __builtin_memcpy(&h, &b, 2); return __bfloat162float(h);
}

// K1: bid [0,512): segmean partial sums (slice sl of batch b, early dispatch);
//     bid [512,640): split gp row-group; [640,688): split W row-group.
// Fragment-linear chunk: dst[((rg*NKS+ks)*2+plane)*64 + lane]; lane l holds
// row rg*16+(l&15), k = ks*32+(l>>4)*8 .. +8.
__global__ __launch_bounds__(512) void k_prep(
    const float* __restrict__ gp, const float* __restrict__ Wm,
    const float* __restrict__ hs,
    const int* __restrict__ gstart, const int* __restrict__ gend,
    short8* __restrict__ a_ws, short8* __restrict__ b_ws,
    float* __restrict__ pp)         // [BB][SEG_SLICES][HH] partial sums
{
    __shared__ __align__(16) float xs[16][LDST];   // 49.4 KB
    const int bid = blockIdx.x;
    const int t = threadIdx.x;

    if (bid < SEG_BLK) {
        if (t < 384) {
            const int b = bid >> 3;
            const int sl = bid & 7;
            const int s0 = gstart[b], e0 = gend[b];
            const int lo = max(s0, sl * 64);
            const int hi = min(e0, sl * 64 + 64);
            const float* base = hs + (size_t)b * LL * HH;
            const int c0 = t, c1 = t + 384;
            float a[2][4];
#pragma unroll
            for (int j = 0; j < 2; ++j)
#pragma unroll
                for (int u = 0; u < 4; ++u) a[j][u] = 0.f;
            int l = lo;
            for (; l + 4 <= hi; l += 4) {
#pragma unroll
                for (int u = 0; u < 4; ++u) {
                    const float* row = base + (size_t)(l + u) * HH;
                    a[0][u] += row[c0]; a[1][u] += row[c1];
                }
            }
            for (; l < hi; ++l) {
                const float* row = base + (size_t)l * HH;
                a[0][0] += row[c0]; a[1][0] += row[c1];
            }
            float* dst = pp + (size_t)bid * HH;
            dst[c0] = (a[0][0] + a[0][1]) + (a[0][2] + a[0][3]);
            dst[c1] = (a[1][0] + a[1][1]) + (a[1][2] + a[1][3]);
        }
    } else {
        const bool isA = bid < SEG_BLK + A_RG;
        const int rg = isA ? (bid - SEG_BLK) : (bid - SEG_BLK - A_RG);
        const float* src = (isA ? gp : Wm) + (size_t)rg * 16 * HH;
        short8* dst = isA ? a_ws : b_ws;

        // coalesced stage: 16 rows x 768 floats, contiguous in global
#pragma unroll
        for (int j = 0; j < 6; ++j) {
            const int idx = t + j * 512;        // 0..3071 float4s
            const int row = idx / 192;
            const int col = (idx - row * 192) * 4;
            *(float4*)&xs[row][col] = *(const float4*)(src + (size_t)idx * 4);
        }
        __syncthreads();

        const int l = t & 63;
        const int cslot = t >> 6;               // 0..7
        const int row = l & 15;
        const int kq = (l >> 4) * 8;
#pragma unroll
        for (int i = 0; i < 3; ++i) {
            const int ks = i * 8 + cslot;
            float xv[8];
            *(float4*)&xv[0] = *(const float4*)&xs[row][ks * 32 + kq];
            *(float4*)&xv[4] = *(const float4*)&xs[row][ks * 32 + kq + 4];
            union { unsigned short u[8]; short8 v; } Hc, Lc;
#pragma unroll
            for (int j = 0; j < 8; ++j) {
                const unsigned short hb = f2bf(xv[j]);
                Hc.u[j] = hb;
                Lc.u[j] = f2bf(xv[j] - bf2f(hb));
            }
            dst[((size_t)(rg * NKS + ks) * 2) * 64 + l]     = Hc.v;
            dst[((size_t)(rg * NKS + ks) * 2 + 1) * 64 + l] = Lc.v;
        }
    }
}

// K2: combine slice partials + LN(g2,b2) -> sel, sgs, sbs, selnorm (+consts b==0)
__global__ __launch_bounds__(256) void k_mid(
    const float* __restrict__ pp,
    const float* __restrict__ g1, const float* __restrict__ b1,
    const float* __restrict__ g2, const float* __restrict__ b2,
    const int* __restrict__ gstart, const int* __restrict__ gend,
    float* __restrict__ sel,
    float* __restrict__ sgs, float* __restrict__ sbs,
    float* __restrict__ selnorm, float* __restrict__ consts)
{
    __shared__ float red[6][4];
    __shared__ float sh2[2];
    const int b = blockIdx.x;
    const int t = threadIdx.x;
    const int s0 = gstart[b], e0 = gend[b];
    const float inv = 1.0f / fmaxf((float)(e0 - s0), 1.0f);
    const int c0 = t, c1 = t + 256, c2 = t + 512;

    float v0 = 0.f, v1 = 0.f, v2 = 0.f;
    const float* base = pp + (size_t)b * SEG_SLICES * HH;
#pragma unroll
    for (int sl = 0; sl < SEG_SLICES; ++sl) {
        v0 += base[(size_t)sl * HH + c0];
        v1 += base[(size_t)sl * HH + c1];
        v2 += base[(size_t)sl * HH + c2];
    }
    v0 *= inv; v1 *= inv; v2 *= inv;

    float s = v0 + v1 + v2;
    float q = v0 * v0 + v1 * v1 + v2 * v2;
    for (int o = 32; o > 0; o >>= 1) {
        s += __shfl_down(s, o, 64);
        q += __shfl_down(q, o, 64);
    }
    const int lane = t & 63, wid = t >> 6;
    if (lane == 0) { red[0][wid] = s; red[1][wid] = q; }
    __syncthreads();
    if (t == 0) {
        const float ts = red[0][0] + red[0][1] + red[0][2] + red[0][3];
        const float tq = red[1][0] + red[1][1] + red[1][2] + red[1][3];
        const float mu = ts / (float)HH;
        const float var = tq / (float)HH - mu * mu;
        sh2[0] = mu; sh2[1] = rsqrtf(var + EPS_LN);
    }
    __syncthreads();
    const float mu = sh2[0], rinv = sh2[1];
    const float g1c0 = g1[c0], g1c1 = g1[c1], g1c2 = g1[c2];
    const float b1c0 = b1[c0], b1c1 = b1[c1], b1c2 = b1[c2];
    const float y0 = (v0 - mu) * rinv * g2[c0] + b2[c0];
    const float y1 = (v1 - mu) * rinv * g2[c1] + b2[c1];
    const float y2 = (v2 - mu) * rinv * g2[c2] + b2[c2];
    sel[(size_t)b * HH + c0] = y0;
    sel[(size_t)b * HH + c1] = y1;
    sel[(size_t)b * HH + c2] = y2;
    float gs = g1c0 * y0 + g1c1 * y1 + g1c2 * y2;
    float bs = b1c0 * y0 + b1c1 * y1 + b1c2 * y2;
    float n  = y0 * y0 + y1 * y1 + y2 * y2;
    float cg2 = g1c0 * g1c0 + g1c1 * g1c1 + g1c2 * g1c2;
    float cgb = g1c0 * b1c0 + g1c1 * b1c1 + g1c2 * b1c2;
    float cb2 = b1c0 * b1c0 + b1c1 * b1c1 + b1c2 * b1c2;
    for (int o = 32; o > 0; o >>= 1) {
        gs += __shfl_down(gs, o, 64);
        bs += __shfl_down(bs, o, 64);
        n  += __shfl_down(n, o, 64);
        cg2 += __shfl_down(cg2, o, 64);
        cgb += __shfl_down(cgb, o, 64);
        cb2 += __shfl_down(cb2, o, 64);
    }
    if (lane == 0) {
        red[0][wid] = gs; red[1][wid] = bs; red[2][wid] = n;
        red[3][wid] = cg2; red[4][wid] = cgb; red[5][wid] = cb2;
    }
    __syncthreads();
    if (t == 0) {
        sgs[b] = red[0][0] + red[0][1] + red[0][2] + red[0][3];
        sbs[b] = red[1][0] + red[1][1] + red[1][2] + red[1][3];
        selnorm[b] = sqrtf(red[2][0] + red[2][1] + red[2][2] + red[2][3]);
        if (b == 0) {
            consts[0] = red[3][0] + red[3][1] + red[3][2] + red[3][3];
            consts[1] = red[4][0] + red[4][1] + red[4][2] + red[4][3];
            consts[2] = red[5][0] + red[5][1] + red[5][2] + red[5][3];
        }
    }
}

// K3: t = gp @ W^T via 3-term bf16-split MFMA (no LDS, no barriers).
// 384 blocks x 4 waves; wave tile = 32m x 32n (2x2 fragments) -> 1536 waves.
// Fused epilogue reduces each wave's 32-col slice to 6 linear partials/row.
#define TRI(ACC, AH_, AL_, BH_, BL_) \
    ACC = __builtin_amdgcn_mfma_f32_16x16x32_bf16(AH_, BH_, ACC, 0, 0, 0); \
    ACC = __builtin_amdgcn_mfma_f32_16x16x32_bf16(AH_, BL_, ACC, 0, 0, 0); \
    ACC = __builtin_amdgcn_mfma_f32_16x16x32_bf16(AL_, BH_, ACC, 0, 0, 0);

#define DECLSET(P) short8 P##a0h,P##a0l,P##a1h,P##a1l,P##b0h,P##b0l,P##b1h,P##b1l;

#define LOADSET(P, KS) { const int o_ = (KS) * 128; \
    P##a0h = ba0[o_]; P##a0l = ba0[o_ + 64]; P##a1h = ba1[o_]; P##a1l = ba1[o_ + 64]; \
    P##b0h = bb0[o_]; P##b0l = bb0[o_ + 64]; P##b1h = bb1[o_]; P##b1l = bb1[o_ + 64]; }

#define MFMASET(P) \
    TRI(acc[0][0], P##a0h, P##a0l, P##b0h, P##b0l) \
    TRI(acc[0][1], P##a0h, P##a0l, P##b1h, P##b1l) \
    TRI(acc[1][0], P##a1h, P##a1l, P##b0h, P##b0l) \
    TRI(acc[1][1], P##a1h, P##a1l, P##b1h, P##b1l)

__global__ __launch_bounds__(256) void k_gemm(
    const short8* __restrict__ aw, const short8* __restrict__ bw,
    const float* __restrict__ bias,
    const float* __restrict__ g1, const float* __restrict__ b1,
    const float* __restrict__ sel,
    float* __restrict__ pp2)        // [NT][MM][6]
{
    const int orig = blockIdx.x;
    const int bid = (orig & 7) * 48 + (orig >> 3);   // XCD swizzle (384 % 8 == 0)
    const int mb = bid / 12;
    const int nb = bid - mb * 12;
    const int wave = threadIdx.x >> 6;
    const int wm = wave >> 1, wn = wave & 1;
    const int lane = threadIdx.x & 63;

    const int mg0 = mb * 4 + wm * 2;
    const int ng0 = nb * 4 + wn * 2;
    const short8* ba0 = aw + (size_t)mg0 * CH_PER_G + lane;
    const short8* ba1 = ba0 + CH_PER_G;
    const short8* bb0 = bw + (size_t)ng0 * CH_PER_G + lane;
    const short8* bb1 = bb0 + CH_PER_G;

    f32x4 acc[2][2] = {};
    DECLSET(A) DECLSET(C)

    LOADSET(A, 0)
    for (int ks = 0; ks < NKS - 2; ks += 2) {
        LOADSET(C, ks + 1)
        MFMASET(A)
        LOADSET(A, ks + 2)
        MFMASET(C)
    }
    LOADSET(C, NKS - 1)
    MFMASET(A)
    MFMASET(C)

    // ---- fused epilogue: 6 linear partials per row over this wave's 32 cols ----
    const int cc = lane & 15;
    const int g = lane >> 4;
    const int bw_ = mb * 2 + wm;            // batch of this wave's 32 rows
    const int ntile = nb * 2 + wn;          // n-tile of 32 cols
    float bias_c[2], gg2[2], ggb[2], ggs[2];
#pragma unroll
    for (int ni = 0; ni < 2; ++ni) {
        const int c = ng0 * 16 + ni * 16 + cc;
        const float g1c = g1[c], b1c = b1[c];
        bias_c[ni] = bias[c];
        gg2[ni] = g1c * g1c;
        ggb[ni] = g1c * b1c;
        ggs[ni] = g1c * sel[(size_t)bw_ * HH + c];
    }
#pragma unroll
    for (int mi = 0; mi < 2; ++mi) {
        float P[4][6];
#pragma unroll
        for (int j = 0; j < 4; ++j)
#pragma unroll
            for (int q = 0; q < 6; ++q) P[j][q] = 0.f;
#pragma unroll
        for (int ni = 0; ni < 2; ++ni)
#pragma unroll
            for (int j = 0; j < 4; ++j) {
                const float tv = acc[mi][ni][j] + bias_c[ni];
                const float tg = tv * gg2[ni];
                P[j][0] += tv;
                P[j][1] = fmaf(tv, tv, P[j][1]);
                P[j][2] += tg;
                P[j][3] = fmaf(tg, tv, P[j][3]);
                P[j][4] = fmaf(tv, ggb[ni], P[j][4]);
                P[j][5] = fmaf(tv, ggs[ni], P[j][5]);
            }
#pragma unroll
        for (int j = 0; j < 4; ++j)
#pragma unroll
            for (int q = 0; q < 6; ++q) {
                float v = P[j][q];
                v += __shfl_xor(v, 1, 64);
                v += __shfl_xor(v, 2, 64);
                v += __shfl_xor(v, 4, 64);
                v += __shfl_xor(v, 8, 64);
                P[j][q] = v;
            }
        if (cc == 0) {
#pragma unroll
            for (int j = 0; j < 4; ++j) {
                const int row = (mg0 + mi) * 16 + g * 4 + j;
                float* dst = pp2 + ((size_t)ntile * MM + row) * 6;
#pragma unroll
                for (int q = 0; q < 6; ++q) dst[q] = P[j][q];
            }
        }
    }
}

// K4: final per-row scalar math from the 24 partial sets. 8 blocks x 256.
__global__ __launch_bounds__(256) void k_comb(
    const float* __restrict__ pp2,
    const float* __restrict__ sgs, const float* __restrict__ sbs,
    const float* __restrict__ selnorm, const float* __restrict__ consts,
    float* __restrict__ out)
{
    const int m = blockIdx.x * 256 + threadIdx.x;
    float S0 = 0.f, S1 = 0.f, S2 = 0.f, S3 = 0.f, S4 = 0.f, S5 = 0.f;
#pragma unroll
    for (int nt = 0; nt < NT; ++nt) {
        const float* p = pp2 + ((size_t)nt * MM + m) * 6;
        S0 += p[0]; S1 += p[1]; S2 += p[2];
        S3 += p[3]; S4 += p[4]; S5 += p[5];
    }
    const int b = m >> 5;
    const float mu = S0 * (1.0f / (float)HH);
    const float var = S1 * (1.0f / (float)HH) - mu * mu;
    const float rinv = rsqrtf(var + EPS_LN);
    const float num = rinv * (S5 - mu * sgs[b]) + sbs[b];
    const float ny2 = rinv * rinv * (S3 - 2.f * mu * S2 + mu * mu * consts[0])
                    + 2.f * rinv * (S4 - mu * consts[1]) + consts[2];
    const float ny = sqrtf(fmaxf(ny2, 0.f));
    out[m] = num / fmaxf(selnorm[b] * ny, EPS_COS);
}

extern "C" void kernel_launch(void* const* d_in, const int* in_sizes, int n_in,
                              void* d_out, int out_size, void* d_ws, size_t ws_size,
                              hipStream_t stream) {
    const float* hs  = (const float*)d_in[0];
    const float* gp  = (const float*)d_in[1];
    const float* W   = (const float*)d_in[2];
    const float* bia = (const float*)d_in[3];
    const float* g1  = (const float*)d_in[4];
    const float* b1  = (const float*)d_in[5];
    const float* g2  = (const float*)d_in[6];
    const float* b2  = (const float*)d_in[7];
    const int* gs    = (const int*)d_in[8];
    const int* ge    = (const int*)d_in[9];
    float* out = (float*)d_out;

    char* ws = (char*)d_ws;
    short8* a_ws  = (short8*)ws;                                        // 6.29 MB
    short8* b_ws  = (short8*)(ws + (size_t)A_RG * CH_PER_G * 16);       // 2.36 MB
    float* pp      = (float*)(ws + (size_t)(A_RG + B_RG) * CH_PER_G * 16); // 1.57 MB
    float* sel     = pp + (size_t)BB * SEG_SLICES * HH;                 // 196 KB
    float* pp2     = sel + (size_t)BB * HH;                             // 1.18 MB
    float* sgs     = pp2 + (size_t)NT * MM * 6;
    float* sbs     = sgs + BB;
    float* selnorm = sbs + BB;
    float* consts  = selnorm + BB;

    k_prep<<<SEG_BLK + A_RG + B_RG, 512, 0, stream>>>(gp, W, hs, gs, ge,
                                                      a_ws, b_ws, pp);
    k_mid<<<BB, 256, 0, stream>>>(pp, g1, b1, g2, b2, gs, ge,
                                  sel, sgs, sbs, selnorm, consts);
    k_gemm<<<NGB, 256, 0, stream>>>(a_ws, b_ws, bia, g1, b1, sel, pp2);
    k_comb<<<MM / 256, 256, 0, stream>>>(pp2, sgs, sbs, selnorm, consts, out);
}

// Round 9
// 28.183 us; speedup vs baseline: 1.4859x; 1.4110x over previous
//
#include <hip/hip_runtime.h>
#include <hip/hip_bf16.h>
#include <math.h>

#define BB 64
#define LL 512
#define HH 768
#define SS 32
#define MM 2048
#define EPS_LN 1e-12f
#define EPS_COS 1e-8f

#define NKS 12                  // k-steps of 64 (i8 MFMA)
#define NGB 384                 // gemm blocks (64m x 64n tiles: 32 x 12)
#define CH_PER_G (NKS * 2 * 64) // int4v chunks per row-group: 1536
#define A_RG (MM / 16)          // 128
#define B_RG (HH / 16)          // 48
#define LDST 772                // LDS row stride (floats)
#define SEG_SLICES 8
#define SEG_BLK (BB * SEG_SLICES)   // 512

#define SCALE_X 4096.0f         // 2^12
#define SCALE_W 131072.0f       // 2^17
#define INV_SC  1.8626451e-9f   // 2^-29

typedef __attribute__((ext_vector_type(4))) int int4v;
typedef __attribute__((ext_vector_type(4))) float f32x4;

static __device__ inline void quant(float x, float scale,
                                    signed char& hi, signed char& lo) {
    int v = (int)rintf(x * scale);
    v = max(-32639, min(32639, v));
    const signed char l8 = (signed char)(v & 0xFF);
    hi = (signed char)((v - (int)l8) >> 8);
    lo = l8;
}

// K1: bid [0,512): segmean partial sums (slice sl of batch b, early dispatch);
//     bid [512,640): quant-split gp row-group; [640,688): quant-split W.
// Chunk layout (int4v units): rg*1536 + ks*128 + plane*64 + lane; lane l holds
// row rg*16+(l&15), k = ks*64 + (l>>4)*16 .. +16 (1 byte per k).
__global__ __launch_bounds__(256) void k_prep(
    const float* __restrict__ gp, const float* __restrict__ Wm,
    const float* __restrict__ hs,
    const int* __restrict__ gstart, const int* __restrict__ gend,
    int4v* __restrict__ a_ws, int4v* __restrict__ b_ws,
    float* __restrict__ pp)         // [BB][SEG_SLICES][HH] partial sums
{
    __shared__ __align__(16) float xs[16][LDST];   // 49.4 KB
    const int bid = blockIdx.x;
    const int t = threadIdx.x;

    if (bid < SEG_BLK) {
        const int b = bid >> 3;
        const int sl = bid & 7;
        const int s0 = gstart[b], e0 = gend[b];
        const int lo = max(s0, sl * 64);
        const int hi = min(e0, sl * 64 + 64);
        const float* base = hs + (size_t)b * LL * HH;
        const int c0 = t, c1 = t + 256, c2 = t + 512;
        float a[3][4];
#pragma unroll
        for (int j = 0; j < 3; ++j)
#pragma unroll
            for (int u = 0; u < 4; ++u) a[j][u] = 0.f;
        int l = lo;
        for (; l + 4 <= hi; l += 4) {
#pragma unroll
            for (int u = 0; u < 4; ++u) {
                const float* row = base + (size_t)(l + u) * HH;
                a[0][u] += row[c0]; a[1][u] += row[c1]; a[2][u] += row[c2];
            }
        }
        for (; l < hi; ++l) {
            const float* row = base + (size_t)l * HH;
            a[0][0] += row[c0]; a[1][0] += row[c1]; a[2][0] += row[c2];
        }
        float* dst = pp + (size_t)bid * HH;
        dst[c0] = (a[0][0] + a[0][1]) + (a[0][2] + a[0][3]);
        dst[c1] = (a[1][0] + a[1][1]) + (a[1][2] + a[1][3]);
        dst[c2] = (a[2][0] + a[2][1]) + (a[2][2] + a[2][3]);
    } else {
        const bool isA = bid < SEG_BLK + A_RG;
        const int rg = isA ? (bid - SEG_BLK) : (bid - SEG_BLK - A_RG);
        const float* src = (isA ? gp : Wm) + (size_t)rg * 16 * HH;
        int4v* dst = isA ? a_ws : b_ws;
        const float sc = isA ? SCALE_X : SCALE_W;

        // coalesced stage: 16 rows x 768 floats, contiguous in global
#pragma unroll
        for (int j = 0; j < 12; ++j) {
            const int idx = t + j * 256;        // 0..3071 float4s
            const int row = idx / 192;
            const int col = (idx - row * 192) * 4;
            *(float4*)&xs[row][col] = *(const float4*)(src + (size_t)idx * 4);
        }
        __syncthreads();

        const int l = t & 63;
        const int cslot = t >> 6;               // 0..3
        const int row = l & 15;
        const int koff = (l >> 4) * 16;
#pragma unroll
        for (int i = 0; i < 3; ++i) {
            const int ks = i * 4 + cslot;
            const int kbase = ks * 64 + koff;
            union { signed char c[16]; int4v v; } Hc, Lc;
#pragma unroll
            for (int q = 0; q < 4; ++q) {
                const float4 xv = *(const float4*)&xs[row][kbase + 4 * q];
                quant(xv.x, sc, Hc.c[4 * q + 0], Lc.c[4 * q + 0]);
                quant(xv.y, sc, Hc.c[4 * q + 1], Lc.c[4 * q + 1]);
                quant(xv.z, sc, Hc.c[4 * q + 2], Lc.c[4 * q + 2]);
                quant(xv.w, sc, Hc.c[4 * q + 3], Lc.c[4 * q + 3]);
            }
            dst[(size_t)(rg * NKS + ks) * 128 + l]      = Hc.v;
            dst[(size_t)(rg * NKS + ks) * 128 + 64 + l] = Lc.v;
        }
    }
}

// K2: blocks [0,384): t = gp @ W^T via 2-chain int8 MFMA (no LDS, no barriers).
//     blocks [384,448): combine segmean partials + LN(g2,b2) -> sel, selnorm.
#define TRIO(MI, NI, AH_, AL_, BH_, BL_) \
    accH[MI][NI] = __builtin_amdgcn_mfma_i32_16x16x64_i8(AH_, BH_, accH[MI][NI], 0, 0, 0); \
    accM[MI][NI] = __builtin_amdgcn_mfma_i32_16x16x64_i8(AH_, BL_, accM[MI][NI], 0, 0, 0); \
    accM[MI][NI] = __builtin_amdgcn_mfma_i32_16x16x64_i8(AL_, BH_, accM[MI][NI], 0, 0, 0);

#define DECLSET(P) int4v P##a0h,P##a0l,P##a1h,P##a1l, \
    P##b0h,P##b0l,P##b1h,P##b1l,P##b2h,P##b2l,P##b3h,P##b3l;

#define LOADSET(P, KS) { const int o_ = (KS) * 128; \
    P##a0h = ba0[o_]; P##a0l = ba0[o_ + 64]; P##a1h = ba1[o_]; P##a1l = ba1[o_ + 64]; \
    P##b0h = bb0[o_]; P##b0l = bb0[o_ + 64]; P##b1h = bb1[o_]; P##b1l = bb1[o_ + 64]; \
    P##b2h = bb2[o_]; P##b2l = bb2[o_ + 64]; P##b3h = bb3[o_]; P##b3l = bb3[o_ + 64]; }

#define MFMASET(P) \
    TRIO(0, 0, P##a0h, P##a0l, P##b0h, P##b0l) \
    TRIO(0, 1, P##a0h, P##a0l, P##b1h, P##b1l) \
    TRIO(0, 2, P##a0h, P##a0l, P##b2h, P##b2l) \
    TRIO(0, 3, P##a0h, P##a0l, P##b3h, P##b3l) \
    TRIO(1, 0, P##a1h, P##a1l, P##b0h, P##b0l) \
    TRIO(1, 1, P##a1h, P##a1l, P##b1h, P##b1l) \
    TRIO(1, 2, P##a1h, P##a1l, P##b2h, P##b2l) \
    TRIO(1, 3, P##a1h, P##a1l, P##b3h, P##b3l)

__global__ __launch_bounds__(128) void k_gemm(
    const int4v* __restrict__ aw, const int4v* __restrict__ bw,
    const float* __restrict__ pp,
    const float* __restrict__ g2, const float* __restrict__ b2,
    const int* __restrict__ gstart, const int* __restrict__ gend,
    float* __restrict__ tbuf, float* __restrict__ sel, float* __restrict__ selnorm)
{
    __shared__ float red[2][2], red2[2], sh2[2];

    if (blockIdx.x < NGB) {
        const int orig = blockIdx.x;
        const int bid = (orig & 7) * 48 + (orig >> 3);   // XCD swizzle (384 % 8 == 0)
        const int mb = bid / 12;
        const int nb = bid - mb * 12;
        const int wave = threadIdx.x >> 6;
        const int lane = threadIdx.x & 63;

        const int mg0 = mb * 4 + wave * 2;
        const int4v* ba0 = aw + (size_t)mg0 * CH_PER_G + lane;
        const int4v* ba1 = ba0 + CH_PER_G;
        const int4v* bb0 = bw + (size_t)(nb * 4) * CH_PER_G + lane;
        const int4v* bb1 = bb0 + CH_PER_G;
        const int4v* bb2 = bb1 + CH_PER_G;
        const int4v* bb3 = bb2 + CH_PER_G;

        int4v accH[2][4] = {};
        int4v accM[2][4] = {};
        DECLSET(A) DECLSET(C)

        LOADSET(A, 0)
        for (int ks = 0; ks < NKS - 2; ks += 2) {
            LOADSET(C, ks + 1)
            MFMASET(A)
            LOADSET(A, ks + 2)
            MFMASET(C)
        }
        LOADSET(C, NKS - 1)
        MFMASET(A)
        MFMASET(C)

        // C frag: col = lane&15, row = (lane>>4)*4 + j; t = (HH*2^16 + M*2^8)*2^-29
        const int wm = mg0 * 16;
        const int wn = nb * 64;
        const int r0 = (lane >> 4) * 4;
        const int cc = lane & 15;
#pragma unroll
        for (int mi = 0; mi < 2; ++mi)
#pragma unroll
            for (int ni = 0; ni < 4; ++ni)
#pragma unroll
                for (int j = 0; j < 4; ++j) {
                    const float tv = ((float)accH[mi][ni][j] * 65536.0f
                                    + (float)accM[mi][ni][j] * 256.0f) * INV_SC;
                    tbuf[(size_t)(wm + mi * 16 + r0 + j) * HH + wn + ni * 16 + cc] = tv;
                }
    } else {
        // -------- combine segmean partials + LN(g2,b2) --------
        const int cb = blockIdx.x - NGB;
        const int t = threadIdx.x;
        const int lane = t & 63, wv = t >> 6;
        const int s0 = gstart[cb], e0 = gend[cb];
        const float inv = 1.0f / fmaxf((float)(e0 - s0), 1.0f);

        float v[6];
#pragma unroll
        for (int j = 0; j < 6; ++j) v[j] = 0.f;
        const float* base = pp + (size_t)cb * SEG_SLICES * HH;
#pragma unroll
        for (int sl = 0; sl < SEG_SLICES; ++sl) {
#pragma unroll
            for (int j = 0; j < 6; ++j)
                v[j] += base[(size_t)sl * HH + t + 128 * j];
        }
        float s = 0.f, q = 0.f;
#pragma unroll
        for (int j = 0; j < 6; ++j) {
            v[j] *= inv;
            s += v[j];
            q = fmaf(v[j], v[j], q);
        }
        for (int o = 32; o > 0; o >>= 1) {
            s += __shfl_xor(s, o, 64);
            q += __shfl_xor(q, o, 64);
        }
        if (lane == 0) { red[0][wv] = s; red[1][wv] = q; }
        __syncthreads();
        if (t == 0) {
            const float ts = red[0][0] + red[0][1];
            const float tq = red[1][0] + red[1][1];
            const float mu = ts / (float)HH;
            const float var = tq / (float)HH - mu * mu;
            sh2[0] = mu;
            sh2[1] = rsqrtf(var + EPS_LN);
        }
        __syncthreads();
        const float mu = sh2[0], rinv = sh2[1];
        float n = 0.f;
#pragma unroll
        for (int j = 0; j < 6; ++j) {
            const int c = t + 128 * j;
            const float y = (v[j] - mu) * rinv * g2[c] + b2[c];
            sel[(size_t)cb * HH + c] = y;
            n = fmaf(y, y, n);
        }
        for (int o = 32; o > 0; o >>= 1) n += __shfl_xor(n, o, 64);
        if (lane == 0) red2[wv] = n;
        __syncthreads();
        if (t == 0) selnorm[cb] = sqrtf(red2[0] + red2[1]);
    }
}

// K3: per-row LN(g1,b1) + cosine vs sel. One wave per t-row; bias folded in.
__global__ __launch_bounds__(512) void k_finish(
    const float* __restrict__ tbuf, const float* __restrict__ bias,
    const float* __restrict__ g1, const float* __restrict__ b1,
    const float* __restrict__ sel, const float* __restrict__ selnorm,
    float* __restrict__ out)
{
    const int lane = threadIdx.x & 63;
    const int w = threadIdx.x >> 6;
    const int m = blockIdx.x * 8 + w;
    const int b = m >> 5;
    const float* trow = tbuf + (size_t)m * HH;

    float v[12];
#pragma unroll
    for (int j = 0; j < 12; ++j) {
        const int col = lane + 64 * j;
        v[j] = trow[col] + bias[col];
    }
    float s = 0.f, q = 0.f;
#pragma unroll
    for (int j = 0; j < 12; ++j) { s += v[j]; q = fmaf(v[j], v[j], q); }
    for (int o = 32; o > 0; o >>= 1) {
        s += __shfl_xor(s, o, 64);
        q += __shfl_xor(q, o, 64);
    }
    const float mu = s * (1.0f / (float)HH);
    const float var = q * (1.0f / (float)HH) - mu * mu;
    const float rinv = rsqrtf(var + EPS_LN);

    const float* selb = sel + (size_t)b * HH;
    float d = 0.f, n2 = 0.f;
#pragma unroll
    for (int j = 0; j < 12; ++j) {
        const int col = lane + 64 * j;
        const float y = (v[j] - mu) * rinv * g1[col] + b1[col];
        d = fmaf(y, selb[col], d);
        n2 = fmaf(y, y, n2);
    }
    for (int o = 32; o > 0; o >>= 1) {
        d += __shfl_xor(d, o, 64);
        n2 += __shfl_xor(n2, o, 64);
    }
    if (lane == 0)
        out[m] = d / fmaxf(selnorm[b] * sqrtf(n2), EPS_COS);
}

extern "C" void kernel_launch(void* const* d_in, const int* in_sizes, int n_in,
                              void* d_out, int out_size, void* d_ws, size_t ws_size,
                              hipStream_t stream) {
    const float* hs  = (const float*)d_in[0];
    const float* gp  = (const float*)d_in[1];
    const float* W   = (const float*)d_in[2];
    const float* bia = (const float*)d_in[3];
    const float* g1  = (const float*)d_in[4];
    const float* b1  = (const float*)d_in[5];
    const float* g2  = (const float*)d_in[6];
    const float* b2  = (const float*)d_in[7];
    const int* gs    = (const int*)d_in[8];
    const int* ge    = (const int*)d_in[9];
    float* out = (float*)d_out;

    char* ws = (char*)d_ws;
    int4v* a_ws  = (int4v*)ws;                                          // 3.15 MB
    int4v* b_ws  = (int4v*)(ws + (size_t)A_RG * CH_PER_G * 16);         // 1.18 MB
    float* pp      = (float*)(ws + (size_t)(A_RG + B_RG) * CH_PER_G * 16); // 1.57 MB
    float* sel     = pp + (size_t)BB * SEG_SLICES * HH;                 // 196 KB
    float* selnorm = sel + (size_t)BB * HH;
    float* tbuf    = selnorm + BB;                                      // 6.29 MB

    k_prep<<<SEG_BLK + A_RG + B_RG, 256, 0, stream>>>(gp, W, hs, gs, ge,
                                                      a_ws, b_ws, pp);
    k_gemm<<<NGB + BB, 128, 0, stream>>>(a_ws, b_ws, pp, g2, b2, gs, ge,
                                         tbuf, sel, selnorm);
    k_finish<<<MM / 8, 512, 0, stream>>>(tbuf, bia, g1, b1, sel, selnorm, out);
}